// Round 3
// baseline (62.369 us; speedup 1.0000x reference)
//
#include <hip/hip_runtime.h>
#include <math.h>

#define NPTS 262144
#define K 32
#define D 16
#define NU 136        // packed upper-triangle count of 16x16 symmetric
#define PSTRIDE 160   // per-k param stride (floats): G[16], U[136], lc, pad
#define LC_OFF (D + NU)   // 152

// ---------------- prep kernel: one block per component k ----------------
// Computes, all in double, then stores float (pre-scaled by log2(e)):
//   G[d]   = log2e * (L m)[d]
//   U[d<=f]= log2e * (d==f ? -0.5*L[d][d] : -L[d][f])
//   lc     = log2e * ( logsoftmax(p)[k] - 8*log(2pi) + log sqrt(det L)
//                      - 0.5 * m^T L m )
// so that density(x) = sum_k exp2( lc + G.x + x^T U x )
__global__ __launch_bounds__(256) void gm_prep_kernel(
    const float* __restrict__ m_w,      // K*D
    const float* __restrict__ l_fac,    // K*D*D
    const float* __restrict__ p_logits, // K
    float* __restrict__ params)         // K*PSTRIDE
{
  const int k = blockIdx.x;
  const int tid = threadIdx.x;
  const int r = tid >> 4, c = tid & 15;
  __shared__ double A[D][D];
  __shared__ double L[D][D];
  __shared__ double W[D][D];   // Cholesky workspace
  __shared__ double Gd[D];
  const double LOG2E = 1.4426950408889634074;

  A[r][c] = (double)l_fac[k * D * D + r * D + c];
  __syncthreads();

  // L = A A^T / D  (full symmetric, one entry per thread)
  {
    double s = 0.0;
    #pragma unroll
    for (int e = 0; e < D; ++e) s += A[r][e] * A[c][e];
    s /= (double)D;
    L[r][c] = s;
    W[r][c] = s;
  }
  __syncthreads();

  // G = L m (double kept in Gd for the m^T L m fold)
  if (tid < D) {
    double s = 0.0;
    #pragma unroll
    for (int f = 0; f < D; ++f) s += L[tid][f] * (double)m_w[k * D + f];
    Gd[tid] = s;
    params[k * PSTRIDE + tid] = (float)(LOG2E * s);
  }

  // packed upper-tri coefficients of -0.5 * x^T L x
  for (int idx = tid; idx < NU; idx += 256) {
    int d = 0, base = 0;
    while (base + (D - d) <= idx) { base += D - d; ++d; }
    int f = d + (idx - base);
    double u = (d == f) ? -0.5 * L[d][f] : -1.0 * L[d][f];
    params[k * PSTRIDE + D + idx] = (float)(LOG2E * u);
  }

  // Cholesky of W (PSD, no pivoting needed) for log sqrt(det L) = sum log C_jj
  for (int j = 0; j < D; ++j) {
    __syncthreads();
    if (tid == 0) W[j][j] = sqrt(W[j][j]);
    __syncthreads();
    if (tid > j && tid < D) W[tid][j] /= W[j][j];
    __syncthreads();
    if (r > j && c > j && c <= r) W[r][c] -= W[r][j] * W[c][j];
  }
  __syncthreads();

  if (tid == 0) {
    double logdet_sqrtL = 0.0;
    for (int j = 0; j < D; ++j) logdet_sqrtL += log(W[j][j]);
    // log-softmax over the K logits (redundant per block; trivial work)
    double mx = -1e300;
    for (int i = 0; i < K; ++i) mx = fmax(mx, (double)p_logits[i]);
    double z = 0.0;
    for (int i = 0; i < K; ++i) z += exp((double)p_logits[i] - mx);
    double logp = (double)p_logits[k] - mx - log(z);
    double cc = 0.0;                       // m^T L m
    for (int d2 = 0; d2 < D; ++d2) cc += (double)m_w[k * D + d2] * Gd[d2];
    double lc = logp - 8.0 * log(2.0 * M_PI) + logdet_sqrtL - 0.5 * cc;
    params[k * PSTRIDE + LC_OFF] = (float)(LOG2E * lc);
  }
}

// ---------------- main kernel ----------------
// K split across waves: block = 256 threads handles 128 points.
// Waves 0-1 (tid<128) do k in [0,16); waves 2-3 do k in [16,32).
// 2048 blocks = 8 blocks/CU = 8 waves/SIMD for latency hiding.
// khalf is forced wave-uniform via readfirstlane so the per-k parameter
// reads stay s_loads (free SGPR operands in v_fma).
__global__ __launch_bounds__(256) void gm_density_kernel(
    const float* __restrict__ x,       // N*D
    const float* __restrict__ params,  // K*PSTRIDE
    float* __restrict__ out)           // N
{
  __shared__ float part[128];
  const int tid = threadIdx.x;
  const int p = tid & 127;
  const int n = blockIdx.x * 128 + p;
  const int khalf = __builtin_amdgcn_readfirstlane(tid >> 7);
  const float* __restrict__ pbase = params + (size_t)khalf * 16 * PSTRIDE;

  float xa[D];
  const float4* xp = (const float4*)(x + (size_t)n * D);
  #pragma unroll
  for (int i = 0; i < 4; ++i) {
    float4 v = xp[i];
    xa[4 * i + 0] = v.x; xa[4 * i + 1] = v.y;
    xa[4 * i + 2] = v.z; xa[4 * i + 3] = v.w;
  }

  float suma = 0.f;
  for (int k = 0; k < 16; ++k) {
    const float* __restrict__ pk = pbase + k * PSTRIDE;
    float ea = pk[LC_OFF];
    const float* __restrict__ U = pk + D;
    int ui = 0;
    #pragma unroll
    for (int d = 0; d < D; ++d) {
      float ta = pk[d];
      #pragma unroll
      for (int f = d; f < D; ++f) {
        float u = U[ui++];
        ta = fmaf(u, xa[f], ta);
      }
      ea = fmaf(xa[d], ta, ea);
    }
    suma += exp2f(ea);
  }

  if (khalf) part[p] = suma;
  __syncthreads();
  if (!khalf) out[n] = suma + part[p];
}

extern "C" void kernel_launch(void* const* d_in, const int* in_sizes, int n_in,
                              void* d_out, int out_size, void* d_ws, size_t ws_size,
                              hipStream_t stream) {
  const float* x        = (const float*)d_in[0];
  const float* m_w      = (const float*)d_in[1];
  const float* l_fac    = (const float*)d_in[2];
  const float* p_logits = (const float*)d_in[3];
  float* out = (float*)d_out;
  float* params = (float*)d_ws;   // K*PSTRIDE floats = 20 KiB

  gm_prep_kernel<<<K, 256, 0, stream>>>(m_w, l_fac, p_logits, params);
  gm_density_kernel<<<NPTS / 128, 256, 0, stream>>>(x, params, out);
}

// Round 4
// 45.518 us; speedup vs baseline: 1.3702x; 1.3702x over previous
//
#include <hip/hip_runtime.h>
#include <math.h>

#define NPTS 262144
#define K 32
#define D 16
#define R 272            // contraction dim: 256 quad (all d,f) + 16 linear
#define NSTEP 17         // R / 16
#define NTILES (NPTS/32) // 8192 tiles of 32 points
#define NWAVES 2048
#define NBLK (NWAVES/4)

typedef __attribute__((ext_vector_type(8))) short bf16x8;   // 8 bf16 = 4 VGPR
typedef __attribute__((ext_vector_type(16))) float f32x16;  // MFMA acc
typedef __attribute__((ext_vector_type(4))) int int4v;

union frag_u { int4v i; bf16x8 h; };

// ---------------- prep kernel: one block per component k ----------------
// All math in double. Produces, pre-scaled by log2(e):
//   Theta[k][r] : r<256 -> -0.5*L[d=r>>4][f=r&15] ; r in [256,272) -> (L m)[r-256]
//   split into bf16 hi (truncation) + bf16 lo (residual) arrays, plus
//   lc[k] = logsoftmax(p)_k - 8 log(2pi) + log sqrt(det L) - 0.5 m^T L m
// so density(x) = sum_k exp2( lc_k + Theta_k . phi(x) ),
// phi(x) = [x_d x_f (256), x_d (16)].
__global__ __launch_bounds__(256) void gm_prep_kernel(
    const float* __restrict__ m_w,      // K*D
    const float* __restrict__ l_fac,    // K*D*D
    const float* __restrict__ p_logits, // K
    unsigned short* __restrict__ thetaH, // K*R bf16 bits
    unsigned short* __restrict__ thetaL, // K*R bf16 bits
    float* __restrict__ lc_out)          // K
{
  const int k = blockIdx.x;
  const int tid = threadIdx.x;
  const int r = tid >> 4, c = tid & 15;
  __shared__ double A[D][D];
  __shared__ double L[D][D];
  __shared__ double W[D][D];   // Cholesky workspace
  __shared__ double Gd[D];
  const double LOG2E = 1.4426950408889634074;

  A[r][c] = (double)l_fac[k * D * D + r * D + c];
  __syncthreads();

  // L = A A^T / D
  {
    double s = 0.0;
    #pragma unroll
    for (int e = 0; e < D; ++e) s += A[r][e] * A[c][e];
    s /= (double)D;
    L[r][c] = s;
    W[r][c] = s;
  }
  __syncthreads();

  // G = L m (kept in double for the m^T L m fold)
  if (tid < D) {
    double s = 0.0;
    #pragma unroll
    for (int f = 0; f < D; ++f) s += L[tid][f] * (double)m_w[k * D + f];
    Gd[tid] = s;
  }

  // Cholesky of W for log sqrt(det L) = sum log W_jj
  for (int j = 0; j < D; ++j) {
    __syncthreads();
    if (tid == 0) W[j][j] = sqrt(W[j][j]);
    __syncthreads();
    if (tid > j && tid < D) W[tid][j] /= W[j][j];
    __syncthreads();
    if (r > j && c > j && c <= r) W[r][c] -= W[r][j] * W[c][j];
  }
  __syncthreads();

  if (tid == 0) {
    double logdet_sqrtL = 0.0;
    for (int j = 0; j < D; ++j) logdet_sqrtL += log(W[j][j]);
    double mx = -1e300;
    for (int i = 0; i < K; ++i) mx = fmax(mx, (double)p_logits[i]);
    double z = 0.0;
    for (int i = 0; i < K; ++i) z += exp((double)p_logits[i] - mx);
    double logp = (double)p_logits[k] - mx - log(z);
    double cc = 0.0;                       // m^T L m
    for (int d2 = 0; d2 < D; ++d2) cc += (double)m_w[k * D + d2] * Gd[d2];
    double lc = logp - 8.0 * log(2.0 * M_PI) + logdet_sqrtL - 0.5 * cc;
    lc_out[k] = (float)(LOG2E * lc);
  }
  __syncthreads();

  // Theta entries, hi/lo bf16 split (truncation; lo absorbs the residual)
  for (int q = tid; q < R; q += 256) {
    double th = (q < 256) ? (-0.5 * LOG2E) * L[q >> 4][q & 15]
                          : LOG2E * Gd[q - 256];
    float tf = (float)th;
    unsigned u = __float_as_uint(tf);
    float hi = __uint_as_float(u & 0xFFFF0000u);
    float lo = tf - hi;
    thetaH[k * R + q] = (unsigned short)(u >> 16);
    thetaL[k * R + q] = (unsigned short)(__float_as_uint(lo) >> 16);
  }
}

// ---------------- density kernel: MFMA over phi(x) ----------------
// Per wave-tile: 32 points. A-operand = Theta (rows = 32 comps), resident in
// VGPRs, hoisted out of the tile loop. B-operand = phi fragments built on the
// fly: lane holds phi[r = s*16 + (lane>>5)*8 + j] for point (lane&31).
// D layout (m74/m101): col=lane&31 (point), row=(reg&3)+8*(reg>>2)+4*(lane>>5)
// (comp). Epilogue: exp2 + tree sum + one shfl_xor(32).
__global__ __launch_bounds__(256, 2) void gm_mfma_kernel(
    const float* __restrict__ x,              // N*D
    const unsigned short* __restrict__ thetaH,
    const unsigned short* __restrict__ thetaL,
    const float* __restrict__ lc,             // K
    float* __restrict__ out)                  // N
{
  const int lane = threadIdx.x & 63;
  const int p = lane & 31;          // point within tile / comp row for A
  const int kh = lane >> 5;         // k-half within 16-wide step
  const int wv = blockIdx.x * 4 + (threadIdx.x >> 6);

  // Theta fragments (A-operand): lane supplies row=comp p, k = kh*8+j
  frag_u TH[NSTEP], TL[NSTEP];
  {
    const char* bh = (const char*)thetaH + p * (R * 2) + kh * 16;
    const char* bl = (const char*)thetaL + p * (R * 2) + kh * 16;
    #pragma unroll
    for (int s = 0; s < NSTEP; ++s) {
      TH[s].i = *(const int4v*)(bh + s * 32);
      TL[s].i = *(const int4v*)(bl + s * 32);
    }
  }
  // lc per accumulator register: comp = (i&3) + 8*(i>>2) + 4*kh
  float lcv[16];
  #pragma unroll
  for (int i = 0; i < 16; ++i)
    lcv[i] = lc[(i & 3) + 8 * (i >> 2) + 4 * kh];

  for (int t = wv; t < NTILES; t += NWAVES) {
    // load this lane's point (both half-waves read the same 64B -> broadcast)
    const float4* xp = (const float4*)(x + ((size_t)t * 32 + p) * D);
    float xs[16];
    #pragma unroll
    for (int i = 0; i < 4; ++i) {
      float4 v = xp[i];
      xs[4 * i + 0] = v.x; xs[4 * i + 1] = v.y;
      xs[4 * i + 2] = v.z; xs[4 * i + 3] = v.w;
    }
    // this lane's f-side slice: x[kh*8 .. kh*8+7]
    float xf[8];
    #pragma unroll
    for (int j = 0; j < 8; ++j) xf[j] = kh ? xs[8 + j] : xs[j];

    f32x16 acc;
    #pragma unroll
    for (int i = 0; i < 16; ++i) acc[i] = 0.f;

    // quad steps s=0..15: phi_r = x_s * x_f, hi/lo split by bit truncation
    #pragma unroll
    for (int s = 0; s < 16; ++s) {
      frag_u ph, pl;
      #pragma unroll
      for (int a = 0; a < 4; ++a) {
        float p0 = xs[s] * xf[2 * a];
        float p1 = xs[s] * xf[2 * a + 1];
        unsigned u0 = __float_as_uint(p0), u1 = __float_as_uint(p1);
        ph.i[a] = (int)__builtin_amdgcn_perm(u1, u0, 0x07060302u);
        float h0 = __uint_as_float(u0 & 0xFFFF0000u);
        float h1 = __uint_as_float(u1 & 0xFFFF0000u);
        float l0 = p0 - h0, l1 = p1 - h1;
        pl.i[a] = (int)__builtin_amdgcn_perm(__float_as_uint(l1),
                                             __float_as_uint(l0), 0x07060302u);
      }
      acc = __builtin_amdgcn_mfma_f32_32x32x16_bf16(TH[s].h, ph.h, acc, 0, 0, 0);
      acc = __builtin_amdgcn_mfma_f32_32x32x16_bf16(TL[s].h, ph.h, acc, 0, 0, 0);
      acc = __builtin_amdgcn_mfma_f32_32x32x16_bf16(TH[s].h, pl.h, acc, 0, 0, 0);
    }
    // linear step s=16: phi_r = x_f
    {
      frag_u ph, pl;
      #pragma unroll
      for (int a = 0; a < 4; ++a) {
        float p0 = xf[2 * a], p1 = xf[2 * a + 1];
        unsigned u0 = __float_as_uint(p0), u1 = __float_as_uint(p1);
        ph.i[a] = (int)__builtin_amdgcn_perm(u1, u0, 0x07060302u);
        float h0 = __uint_as_float(u0 & 0xFFFF0000u);
        float h1 = __uint_as_float(u1 & 0xFFFF0000u);
        float l0 = p0 - h0, l1 = p1 - h1;
        pl.i[a] = (int)__builtin_amdgcn_perm(__float_as_uint(l1),
                                             __float_as_uint(l0), 0x07060302u);
      }
      acc = __builtin_amdgcn_mfma_f32_32x32x16_bf16(TH[16].h, ph.h, acc, 0, 0, 0);
      acc = __builtin_amdgcn_mfma_f32_32x32x16_bf16(TL[16].h, ph.h, acc, 0, 0, 0);
      acc = __builtin_amdgcn_mfma_f32_32x32x16_bf16(TH[16].h, pl.h, acc, 0, 0, 0);
    }

    // epilogue: exp2 per comp, sum 16 local comps, one cross-half add
    float e[16];
    #pragma unroll
    for (int i = 0; i < 16; ++i)
      e[i] = __builtin_amdgcn_exp2f(acc[i] + lcv[i]);
    float a0 = (e[0] + e[1]) + (e[2] + e[3]);
    float a1 = (e[4] + e[5]) + (e[6] + e[7]);
    float a2 = (e[8] + e[9]) + (e[10] + e[11]);
    float a3 = (e[12] + e[13]) + (e[14] + e[15]);
    float ss = (a0 + a1) + (a2 + a3);
    ss += __shfl_xor(ss, 32);
    if (lane < 32) out[(size_t)t * 32 + p] = ss;
  }
}

extern "C" void kernel_launch(void* const* d_in, const int* in_sizes, int n_in,
                              void* d_out, int out_size, void* d_ws, size_t ws_size,
                              hipStream_t stream) {
  const float* x        = (const float*)d_in[0];
  const float* m_w      = (const float*)d_in[1];
  const float* l_fac    = (const float*)d_in[2];
  const float* p_logits = (const float*)d_in[3];
  float* out = (float*)d_out;

  char* ws = (char*)d_ws;
  unsigned short* thetaH = (unsigned short*)(ws);                 // 17408 B
  unsigned short* thetaL = (unsigned short*)(ws + K * R * 2);     // 17408 B
  float* lc              = (float*)(ws + 2 * K * R * 2);          // 128 B

  gm_prep_kernel<<<K, 256, 0, stream>>>(m_w, l_fac, p_logits, thetaH, thetaL, lc);
  gm_mfma_kernel<<<NBLK, 256, 0, stream>>>(x, thetaH, thetaL, lc, out);
}

// Round 5
// 39.595 us; speedup vs baseline: 1.5752x; 1.1496x over previous
//
#include <hip/hip_runtime.h>
#include <math.h>

#define NPTS 262144
#define K 32
#define D 16
#define R 272            // contraction dim: 256 quad (all d,f) + 16 linear
#define NTILES (NPTS/32) // 8192 tiles of 32 points
#define NBLK 1024        // 4 waves/block, 2 tiles/wave -> 8192 tiles
#define LROW 544         // 272 bf16 = 34 x 16B granules per theta row
#define LHALF 17408      // 32 rows * 544 B ; thetaL LDS region offset

typedef __attribute__((ext_vector_type(8))) short bf16x8;   // 8 bf16 = 4 VGPR
typedef __attribute__((ext_vector_type(16))) float f32x16;  // MFMA acc
typedef __attribute__((ext_vector_type(4))) int int4v;

// ---------------- prep kernel: one block per component k ----------------
// All math in double. Produces, pre-scaled by log2(e):
//   Theta[k][r] : r<256 -> -0.5*L[d=r>>4][f=r&15] ; r in [256,272) -> (L m)[r-256]
//   split into bf16 hi (truncation) + bf16 lo (residual) arrays, plus
//   lc[k] = logsoftmax(p)_k - 8 log(2pi) + log sqrt(det L) - 0.5 m^T L m
// so density(x) = sum_k exp2( lc_k + Theta_k . phi(x) ),
// phi(x) = [x_d x_f (256), x_d (16)].
__global__ __launch_bounds__(256) void gm_prep_kernel(
    const float* __restrict__ m_w,      // K*D
    const float* __restrict__ l_fac,    // K*D*D
    const float* __restrict__ p_logits, // K
    unsigned short* __restrict__ thetaH, // K*R bf16 bits
    unsigned short* __restrict__ thetaL, // K*R bf16 bits
    float* __restrict__ lc_out)          // K
{
  const int k = blockIdx.x;
  const int tid = threadIdx.x;
  const int r = tid >> 4, c = tid & 15;
  __shared__ double A[D][D];
  __shared__ double L[D][D];
  __shared__ double W[D][D];   // Cholesky workspace
  __shared__ double Gd[D];
  const double LOG2E = 1.4426950408889634074;

  A[r][c] = (double)l_fac[k * D * D + r * D + c];
  __syncthreads();

  // L = A A^T / D
  {
    double s = 0.0;
    #pragma unroll
    for (int e = 0; e < D; ++e) s += A[r][e] * A[c][e];
    s /= (double)D;
    L[r][c] = s;
    W[r][c] = s;
  }
  __syncthreads();

  // G = L m (kept in double for the m^T L m fold)
  if (tid < D) {
    double s = 0.0;
    #pragma unroll
    for (int f = 0; f < D; ++f) s += L[tid][f] * (double)m_w[k * D + f];
    Gd[tid] = s;
  }

  // Cholesky of W for log sqrt(det L) = sum log W_jj
  for (int j = 0; j < D; ++j) {
    __syncthreads();
    if (tid == 0) W[j][j] = sqrt(W[j][j]);
    __syncthreads();
    if (tid > j && tid < D) W[tid][j] /= W[j][j];
    __syncthreads();
    if (r > j && c > j && c <= r) W[r][c] -= W[r][j] * W[c][j];
  }
  __syncthreads();

  if (tid == 0) {
    double logdet_sqrtL = 0.0;
    for (int j = 0; j < D; ++j) logdet_sqrtL += log(W[j][j]);
    double mx = -1e300;
    for (int i = 0; i < K; ++i) mx = fmax(mx, (double)p_logits[i]);
    double z = 0.0;
    for (int i = 0; i < K; ++i) z += exp((double)p_logits[i] - mx);
    double logp = (double)p_logits[k] - mx - log(z);
    double cc = 0.0;                       // m^T L m
    for (int d2 = 0; d2 < D; ++d2) cc += (double)m_w[k * D + d2] * Gd[d2];
    double lc = logp - 8.0 * log(2.0 * M_PI) + logdet_sqrtL - 0.5 * cc;
    lc_out[k] = (float)(LOG2E * lc);
  }
  __syncthreads();

  // Theta entries, hi/lo bf16 split (truncation; lo absorbs the residual)
  for (int q = tid; q < R; q += 256) {
    double th = (q < 256) ? (-0.5 * LOG2E) * L[q >> 4][q & 15]
                          : LOG2E * Gd[q - 256];
    float tf = (float)th;
    unsigned u = __float_as_uint(tf);
    float hi = __uint_as_float(u & 0xFFFF0000u);
    float lo = tf - hi;
    thetaH[k * R + q] = (unsigned short)(u >> 16);
    thetaL[k * R + q] = (unsigned short)(__float_as_uint(lo) >> 16);
  }
}

// pack 2 floats -> 2 bf16 (truncation) in one dword
__device__ __forceinline__ int pack_bf16_hi(unsigned u0, unsigned u1) {
  return (int)__builtin_amdgcn_perm(u1, u0, 0x07060302u);
}

// ---------------- density kernel: MFMA over phi(x), theta in LDS ----------------
// Theta (hi+lo) staged into LDS with a 16B-granule XOR swizzle
// (phys = m ^ (row&7) ^ (row>>3) for m<32) so the per-step ds_read_b128
// (lane row = lane&31, stride 544 B) is bank-conflict-free.
// Fragments: A = theta row p (comp), k-slot kh*8+j; B = phi built in-register.
// D layout: col=lane&31 (point), row=(reg&3)+8*(reg>>2)+4*kh (comp).
__global__ __launch_bounds__(256, 4) void gm_mfma_kernel(
    const float* __restrict__ x,              // N*D
    const unsigned short* __restrict__ thetaH,
    const unsigned short* __restrict__ thetaL,
    const float* __restrict__ lc,             // K
    float* __restrict__ out)                  // N
{
  __shared__ __align__(16) char lth[2 * LHALF];
  const int tid = threadIdx.x;
  const int lane = tid & 63;
  const int p = lane & 31;          // point within tile / comp row for A
  const int kh = lane >> 5;         // k-half within 16-wide step

  // ---- stage theta -> LDS (swizzled), 2176 16B chunks ----
  for (int j = tid; j < 2176; j += 256) {
    int half = (j >= 1088) ? 1 : 0;
    int jj = half ? j - 1088 : j;
    int row = jj / 34;
    int m = jj - row * 34;
    int sig = (row & 7) ^ (row >> 3);
    int phys = (m < 32) ? (m ^ sig) : m;
    const char* src = (const char*)(half ? thetaL : thetaH) + (size_t)jj * 16;
    int4v v = *(const int4v*)src;
    *(int4v*)(lth + half * LHALF + row * LROW + phys * 16) = v;
  }

  // lc per accumulator register: comp = (i&3) + 8*(i>>2) + 4*kh
  float lcv[16];
  #pragma unroll
  for (int i = 0; i < 16; ++i)
    lcv[i] = lc[(i & 3) + 8 * (i >> 2) + 4 * kh];

  __syncthreads();

  // per-lane swizzled read bases: slot m = kh + 2s, phys = m ^ sig
  // addr = p*544 + 16*((kh^(sig&1)) | ((2s)^(sig&6))) = base2 + ((s*32) ^ E)
  const int sig = (p & 7) ^ (p >> 3);
  const int base2 = p * LROW + ((kh ^ (sig & 1)) << 4);
  const int E = (sig & 6) << 4;
  const int baseT = p * LROW + 512 + (kh << 4);   // tail slot m=32+kh (no swizzle)

  const int t0 = (blockIdx.x * 4 + (tid >> 6)) * 2;

  for (int tt = 0; tt < 2; ++tt) {
    const int t = t0 + tt;
    // load this lane's point (half-waves share addresses -> broadcast)
    const float4* xp = (const float4*)(x + ((size_t)t * 32 + p) * D);
    float xs[16];
    #pragma unroll
    for (int i = 0; i < 4; ++i) {
      float4 v = xp[i];
      xs[4 * i + 0] = v.x; xs[4 * i + 1] = v.y;
      xs[4 * i + 2] = v.z; xs[4 * i + 3] = v.w;
    }
    float xf[8];
    #pragma unroll
    for (int j = 0; j < 8; ++j) xf[j] = kh ? xs[8 + j] : xs[j];

    f32x16 acc;
    #pragma unroll
    for (int i = 0; i < 16; ++i) acc[i] = 0.f;

    // quad steps s=0..15: phi_r = x_s * x_f, hi/lo split by truncation
    #pragma unroll
    for (int s = 0; s < 16; ++s) {
      const int va = base2 + ((s * 32) ^ E);
      int4v thv = *(const int4v*)(lth + va);
      int4v tlv = *(const int4v*)(lth + va + LHALF);
      int4v ph, pl;
      #pragma unroll
      for (int a = 0; a < 4; ++a) {
        float p0 = xs[s] * xf[2 * a];
        float p1 = xs[s] * xf[2 * a + 1];
        unsigned u0 = __float_as_uint(p0), u1 = __float_as_uint(p1);
        ph[a] = pack_bf16_hi(u0, u1);
        float h0 = __uint_as_float(u0 & 0xFFFF0000u);
        float h1 = __uint_as_float(u1 & 0xFFFF0000u);
        pl[a] = pack_bf16_hi(__float_as_uint(p0 - h0), __float_as_uint(p1 - h1));
      }
      acc = __builtin_amdgcn_mfma_f32_32x32x16_bf16(
          __builtin_bit_cast(bf16x8, thv), __builtin_bit_cast(bf16x8, ph), acc, 0, 0, 0);
      acc = __builtin_amdgcn_mfma_f32_32x32x16_bf16(
          __builtin_bit_cast(bf16x8, tlv), __builtin_bit_cast(bf16x8, ph), acc, 0, 0, 0);
      acc = __builtin_amdgcn_mfma_f32_32x32x16_bf16(
          __builtin_bit_cast(bf16x8, thv), __builtin_bit_cast(bf16x8, pl), acc, 0, 0, 0);
    }
    // linear step: phi_r = x_f
    {
      int4v thv = *(const int4v*)(lth + baseT);
      int4v tlv = *(const int4v*)(lth + baseT + LHALF);
      int4v ph, pl;
      #pragma unroll
      for (int a = 0; a < 4; ++a) {
        float p0 = xf[2 * a], p1 = xf[2 * a + 1];
        unsigned u0 = __float_as_uint(p0), u1 = __float_as_uint(p1);
        ph[a] = pack_bf16_hi(u0, u1);
        float h0 = __uint_as_float(u0 & 0xFFFF0000u);
        float h1 = __uint_as_float(u1 & 0xFFFF0000u);
        pl[a] = pack_bf16_hi(__float_as_uint(p0 - h0), __float_as_uint(p1 - h1));
      }
      acc = __builtin_amdgcn_mfma_f32_32x32x16_bf16(
          __builtin_bit_cast(bf16x8, thv), __builtin_bit_cast(bf16x8, ph), acc, 0, 0, 0);
      acc = __builtin_amdgcn_mfma_f32_32x32x16_bf16(
          __builtin_bit_cast(bf16x8, tlv), __builtin_bit_cast(bf16x8, ph), acc, 0, 0, 0);
      acc = __builtin_amdgcn_mfma_f32_32x32x16_bf16(
          __builtin_bit_cast(bf16x8, thv), __builtin_bit_cast(bf16x8, pl), acc, 0, 0, 0);
    }

    // epilogue: exp2 per comp, sum 16 local comps, one cross-half add
    float e[16];
    #pragma unroll
    for (int i = 0; i < 16; ++i)
      e[i] = __builtin_amdgcn_exp2f(acc[i] + lcv[i]);
    float a0 = (e[0] + e[1]) + (e[2] + e[3]);
    float a1 = (e[4] + e[5]) + (e[6] + e[7]);
    float a2 = (e[8] + e[9]) + (e[10] + e[11]);
    float a3 = (e[12] + e[13]) + (e[14] + e[15]);
    float ss = (a0 + a1) + (a2 + a3);
    ss += __shfl_xor(ss, 32);
    if (lane < 32) out[(size_t)t * 32 + p] = ss;
  }
}

extern "C" void kernel_launch(void* const* d_in, const int* in_sizes, int n_in,
                              void* d_out, int out_size, void* d_ws, size_t ws_size,
                              hipStream_t stream) {
  const float* x        = (const float*)d_in[0];
  const float* m_w      = (const float*)d_in[1];
  const float* l_fac    = (const float*)d_in[2];
  const float* p_logits = (const float*)d_in[3];
  float* out = (float*)d_out;

  char* ws = (char*)d_ws;
  unsigned short* thetaH = (unsigned short*)(ws);                 // 17408 B
  unsigned short* thetaL = (unsigned short*)(ws + K * R * 2);     // 17408 B
  float* lc              = (float*)(ws + 2 * K * R * 2);          // 128 B

  gm_prep_kernel<<<K, 256, 0, stream>>>(m_w, l_fac, p_logits, thetaH, thetaL, lc);
  gm_mfma_kernel<<<NBLK, 256, 0, stream>>>(x, thetaH, thetaL, lc, out);
}